// Round 3
// baseline (8629.039 us; speedup 1.0000x reference)
//
#include <hip/hip_runtime.h>
#include <hip/hip_bf16.h>

#define B_  256
#define T_  256
#define F_  64
#define U_  512
#define NG_ 2048   // 4*U
#define BU_ (B_ * U_)

typedef __attribute__((ext_vector_type(8))) short short8;
typedef __attribute__((ext_vector_type(16))) float floatx16;

__device__ __forceinline__ unsigned short f2bf(float f) {
    union { float f; unsigned int u; } v; v.f = f;
    unsigned int u = v.u;
    return (unsigned short)((u + 0x7FFFu + ((u >> 16) & 1u)) >> 16);
}
__device__ __forceinline__ float bf2f(unsigned short s) {
    union { unsigned int u; float f; } v; v.u = ((unsigned int)s) << 16;
    return v.f;
}

__global__ void cast_x_kernel(const float* __restrict__ x,
                              unsigned short* __restrict__ xb, int n) {
    int i = blockIdx.x * blockDim.x + threadIdx.x;
    if (i < n) xb[i] = f2bf(x[i]);
}

// Pack weights into 32x32x16 MFMA B-fragments, per unit-group (16 units -> 64
// block-local gate cols = 2 n32 tiles: [i16|f16] [g16|o16]).
// dst[(((ug*2+nt)*KT + kt)*512) + lane*8 + j] =
//    M[k = kt*16 + (lane>>5)*8 + j][n = (c>>4)*512 + ug*16 + (c&15)], c=nt*32+(lane&31)
// k < KX -> W, else Uw.  (self-consistent A/B k-permutation cancels in MFMA)
__global__ void pack32_kernel(const float* __restrict__ W, const float* __restrict__ Uw,
                              unsigned short* __restrict__ dst, int KT, int KX) {
    long tid = (long)blockIdx.x * blockDim.x + threadIdx.x;
    long total = 32L * 2 * KT * 512;
    if (tid >= total) return;
    int j    = (int)(tid & 7);
    int lane = (int)((tid >> 3) & 63);
    int p512 = (int)(tid >> 9);
    int kt   = p512 % KT;
    int q    = p512 / KT;
    int nt   = q & 1;
    int ug   = q >> 1;
    int c    = nt * 32 + (lane & 31);
    int srcn = (c >> 4) * U_ + ug * 16 + (c & 15);
    int k    = kt * 16 + (lane >> 5) * 8 + j;
    float v  = (k < KX) ? W[(long)k * NG_ + srcn] : Uw[(long)(k - KX) * NG_ + srcn];
    dst[tid] = f2bf(v);
}

__device__ __forceinline__ void wait_ge(int* p, int v) {
    int guard = 0;
    while (__hip_atomic_load(p, __ATOMIC_ACQUIRE, __HIP_MEMORY_SCOPE_AGENT) < v) {
        __builtin_amdgcn_s_sleep(2);
        if (++guard > (1 << 22)) break;   // safety valve: fail visibly, not hang
    }
}
__device__ __forceinline__ void release_add(int* p) {
    __hip_atomic_fetch_add(p, 1, __ATOMIC_RELEASE, __HIP_MEMORY_SCOPE_AGENT);
}

#define MFMA32(a, b, c) __builtin_amdgcn_mfma_f32_32x32x16_bf16(a, b, c, 0, 0, 0)

// Persistent 2-layer LSTM. 256 blocks x 256 thr = 1 block/CU (co-residency is
// structurally guaranteed; no cooperative launch needed).
// Block (mo,ug): 32 batch rows x 16 units, BOTH layers, pipeline skew 1:
//   iter k: phase A = L1 step k, phase B = L2 step k-1.
// Weights for both layers live in VGPRs (~200/lane). 4 waves k-split each GEMM.
__global__ __launch_bounds__(256, 1) void lstm_persist(
    const unsigned short* __restrict__ xb,
    const unsigned short* __restrict__ P1,
    const unsigned short* __restrict__ P2,
    const float* __restrict__ b1, const float* __restrict__ b2,
    unsigned short* __restrict__ h1r, unsigned short* __restrict__ h2r,
    int* cnt1, int* cnt2)
{
    const int bid  = blockIdx.x;     // 0..255
    const int mo   = bid >> 5;       // 8 m-octiles (32 rows each)
    const int ug   = bid & 31;       // 32 unit-groups (16 units each); xcd=bid%8 spreads ug
    const int tid  = threadIdx.x;
    const int w    = tid >> 6;       // wave 0..3 (k-split)
    const int lane = tid & 63;
    const int arow = lane & 31;
    const int koff = (lane >> 5) * 8;
    const int row  = mo * 32 + arow;

    __shared__ float red[4][2][32][32];   // 32 KB k-split partial exchange
    __shared__ float cst1[32][16];        // L1 cell state (fp32, persistent)
    __shared__ float cst2[32][16];        // L2 cell state
    __shared__ float bias1_s[64], bias2_s[64];

    for (int i = tid; i < 512; i += 256) {
        cst1[i >> 4][i & 15] = 0.f;
        cst2[i >> 4][i & 15] = 0.f;
    }
    if (tid < 64) {
        bias1_s[tid] = b1[(tid >> 4) * U_ + ug * 16 + (tid & 15)];
        bias2_s[tid] = b2[(tid >> 4) * U_ + ug * 16 + (tid & 15)];
    }

    // ---- load BOTH layers' B-fragments into registers (once) ----
    short8 a1f0[9], a1f1[9];     // L1: 36 ktiles of K=16, 9 per wave
    {
        const unsigned short* base = P1 + (size_t)ug * (2 * 36 * 512);
        #pragma unroll
        for (int i = 0; i < 9; ++i) {
            a1f0[i] = *(const short8*)(base + ((size_t)(0 * 36 + w * 9 + i) * 64 + lane) * 8);
            a1f1[i] = *(const short8*)(base + ((size_t)(1 * 36 + w * 9 + i) * 64 + lane) * 8);
        }
    }
    short8 b2f0[16], b2f1[16];   // L2: 64 ktiles; w0,w1 -> U2 half; w2,w3 -> W2 half
    {
        const unsigned short* base = P2 + (size_t)ug * (2 * 64 * 512);
        const int fb = (w < 2) ? (32 + w * 16) : ((w - 2) * 16);
        #pragma unroll
        for (int i = 0; i < 16; ++i) {
            b2f0[i] = *(const short8*)(base + ((size_t)(0 * 64 + fb + i) * 64 + lane) * 8);
            b2f1[i] = *(const short8*)(base + ((size_t)(1 * 64 + fb + i) * 64 + lane) * 8);
        }
    }
    __syncthreads();

    for (int k = 0; k <= T_; ++k) {
        // ================= phase A : layer-1 step t = k =================
        if (k < T_) {
            floatx16 acc0, acc1;
            #pragma unroll
            for (int i = 0; i < 16; ++i) { acc0[i] = 0.f; acc1[i] = 0.f; }

            if (w == 0) {
                // x-part first (no dependency), then wait for h1[k-1]
                const unsigned short* xbase = xb + ((size_t)row * T_ + k) * F_;
                #pragma unroll
                for (int i = 0; i < 4; ++i) {
                    short8 a = *(const short8*)(xbase + i * 16 + koff);
                    acc0 = MFMA32(a, a1f0[i], acc0);
                    acc1 = MFMA32(a, a1f1[i], acc1);
                }
                if (k > 0) {
                    wait_ge(cnt1 + (k - 1) * 8 + mo, 32);
                    const unsigned short* hb = h1r + (size_t)((k - 1) & 3) * BU_
                                               + (size_t)row * U_;
                    #pragma unroll
                    for (int i = 4; i < 9; ++i) {
                        short8 a = *(const short8*)(hb + (i - 4) * 16 + koff);
                        acc0 = MFMA32(a, a1f0[i], acc0);
                        acc1 = MFMA32(a, a1f1[i], acc1);
                    }
                }
            } else if (k > 0) {
                wait_ge(cnt1 + (k - 1) * 8 + mo, 32);
                const unsigned short* hb = h1r + (size_t)((k - 1) & 3) * BU_
                                           + (size_t)row * U_ + (w * 9 - 4) * 16;
                #pragma unroll
                for (int i = 0; i < 9; ++i) {
                    short8 a = *(const short8*)(hb + i * 16 + koff);
                    acc0 = MFMA32(a, a1f0[i], acc0);
                    acc1 = MFMA32(a, a1f1[i], acc1);
                }
            }

            // k-split reduce. D layout: col=lane&31, row=(r&3)+8*(r>>2)+4*(lane>>5)
            #pragma unroll
            for (int r = 0; r < 16; ++r) {
                int rr = (r & 3) + 8 * (r >> 2) + 4 * (lane >> 5);
                red[w][0][rr][arow] = acc0[r];
                red[w][1][rr][arow] = acc1[r];
            }
            __syncthreads();

            {   // epilogue: 256 thr x 2 rows
                int u  = tid & 15;
                int r0 = tid >> 4;
                unsigned short* hout = h1r + (size_t)(k & 3) * BU_;
                #pragma unroll
                for (int rh = 0; rh < 2; ++rh) {
                    int r = r0 + rh * 16;
                    float zi = 0.f, zf = 0.f, zg = 0.f, zo = 0.f;
                    #pragma unroll
                    for (int ww = 0; ww < 4; ++ww) {
                        zi += red[ww][0][r][u];
                        zf += red[ww][0][r][16 + u];
                        zg += red[ww][1][r][u];
                        zo += red[ww][1][r][16 + u];
                    }
                    zi += bias1_s[u];      zf += bias1_s[16 + u];
                    zg += bias1_s[32 + u]; zo += bias1_s[48 + u];
                    float si = 1.f / (1.f + __expf(-zi));
                    float sf = 1.f / (1.f + __expf(-zf));
                    float so = 1.f / (1.f + __expf(-zo));
                    float gg = zg > 0.f ? zg : 0.f;
                    float cn = sf * cst1[r][u] + si * gg;
                    cst1[r][u] = cn;
                    float hn = so * (cn > 0.f ? cn : 0.f);
                    hout[(size_t)(mo * 32 + r) * U_ + ug * 16 + u] = f2bf(hn);
                }
            }
            __syncthreads();   // h1 stores drained (vmcnt) + red reads done
            if (tid == 0) release_add(cnt1 + k * 8 + mo);
        }

        // ================= phase B : layer-2 step t2 = k-1 =================
        if (k >= 1) {
            const int t2 = k - 1;
            floatx16 acc0, acc1;
            #pragma unroll
            for (int i = 0; i < 16; ++i) { acc0[i] = 0.f; acc1[i] = 0.f; }

            if (w < 2) {
                // U2 * h2[t2-1] half
                if (t2 > 0) {
                    wait_ge(cnt2 + (t2 - 1) * 8 + mo, 32);
                    const unsigned short* hb = h2r + (size_t)((t2 - 1) & 3) * BU_
                                               + (size_t)row * U_ + (w * 16) * 16;
                    #pragma unroll
                    for (int i = 0; i < 16; ++i) {
                        short8 a = *(const short8*)(hb + i * 16 + koff);
                        acc0 = MFMA32(a, b2f0[i], acc0);
                        acc1 = MFMA32(a, b2f1[i], acc1);
                    }
                }
            } else {
                // W2 * h1[t2] half
                wait_ge(cnt1 + t2 * 8 + mo, 32);
                const unsigned short* hb = h1r + (size_t)(t2 & 3) * BU_
                                           + (size_t)row * U_ + ((w - 2) * 16) * 16;
                #pragma unroll
                for (int i = 0; i < 16; ++i) {
                    short8 a = *(const short8*)(hb + i * 16 + koff);
                    acc0 = MFMA32(a, b2f0[i], acc0);
                    acc1 = MFMA32(a, b2f1[i], acc1);
                }
            }

            #pragma unroll
            for (int r = 0; r < 16; ++r) {
                int rr = (r & 3) + 8 * (r >> 2) + 4 * (lane >> 5);
                red[w][0][rr][arow] = acc0[r];
                red[w][1][rr][arow] = acc1[r];
            }
            __syncthreads();

            {
                int u  = tid & 15;
                int r0 = tid >> 4;
                unsigned short* hout = h2r + (size_t)(t2 & 3) * BU_;
                #pragma unroll
                for (int rh = 0; rh < 2; ++rh) {
                    int r = r0 + rh * 16;
                    float zi = 0.f, zf = 0.f, zg = 0.f, zo = 0.f;
                    #pragma unroll
                    for (int ww = 0; ww < 4; ++ww) {
                        zi += red[ww][0][r][u];
                        zf += red[ww][0][r][16 + u];
                        zg += red[ww][1][r][u];
                        zo += red[ww][1][r][16 + u];
                    }
                    zi += bias2_s[u];      zf += bias2_s[16 + u];
                    zg += bias2_s[32 + u]; zo += bias2_s[48 + u];
                    float si = 1.f / (1.f + __expf(-zi));
                    float sf = 1.f / (1.f + __expf(-zf));
                    float so = 1.f / (1.f + __expf(-zo));
                    float gg = zg > 0.f ? zg : 0.f;
                    float cn = sf * cst2[r][u] + si * gg;
                    cst2[r][u] = cn;
                    float hn = so * (cn > 0.f ? cn : 0.f);
                    hout[(size_t)(mo * 32 + r) * U_ + ug * 16 + u] = f2bf(hn);
                }
            }
            __syncthreads();
            if (tid == 0) release_add(cnt2 + t2 * 8 + mo);
        }
    }
}

__global__ void dense_kernel(const unsigned short* __restrict__ h2,
                             const float* __restrict__ Wd,
                             const float* __restrict__ bd,
                             float* __restrict__ out) {
    int b = blockIdx.x;
    int lane = threadIdx.x;                  // 64 lanes
    const unsigned short* hp = h2 + (long)b * U_ + lane * 8;
    float sum = 0.f;
    #pragma unroll
    for (int j = 0; j < 8; ++j) sum += bf2f(hp[j]) * Wd[lane * 8 + j];
    #pragma unroll
    for (int off = 32; off; off >>= 1) sum += __shfl_down(sum, off);
    if (lane == 0) out[b] = 1.f / (1.f + __expf(-(sum + bd[0])));
}

extern "C" void kernel_launch(void* const* d_in, const int* in_sizes, int n_in,
                              void* d_out, int out_size, void* d_ws, size_t ws_size,
                              hipStream_t stream) {
    const float* x  = (const float*)d_in[0];
    const float* W1 = (const float*)d_in[1];
    const float* U1 = (const float*)d_in[2];
    const float* b1 = (const float*)d_in[3];
    const float* W2 = (const float*)d_in[4];
    const float* U2 = (const float*)d_in[5];
    const float* b2 = (const float*)d_in[6];
    const float* Wd = (const float*)d_in[7];
    const float* bd = (const float*)d_in[8];
    float* out = (float*)d_out;

    char* ws = (char*)d_ws;
    size_t off = 0;
    unsigned short* xb  = (unsigned short*)(ws + off); off += (size_t)B_ * T_ * F_ * 2;      // 8.39 MB
    unsigned short* P1  = (unsigned short*)(ws + off); off += (size_t)32 * 2 * 36 * 512 * 2; // 2.36 MB
    unsigned short* P2  = (unsigned short*)(ws + off); off += (size_t)32 * 2 * 64 * 512 * 2; // 4.19 MB
    unsigned short* h1r = (unsigned short*)(ws + off); off += (size_t)4 * BU_ * 2;           // 1 MB
    unsigned short* h2r = (unsigned short*)(ws + off); off += (size_t)4 * BU_ * 2;           // 1 MB
    int* cnt1 = (int*)(ws + off); off += (size_t)T_ * 8 * 4;
    int* cnt2 = (int*)(ws + off); off += (size_t)T_ * 8 * 4;

    hipMemsetAsync(cnt1, 0, (size_t)T_ * 8 * 4 * 2, stream);

    int n = B_ * T_ * F_;
    cast_x_kernel<<<(n + 255) / 256, 256, 0, stream>>>(x, xb, n);
    {
        long tot1 = 32L * 2 * 36 * 512;
        pack32_kernel<<<(int)((tot1 + 255) / 256), 256, 0, stream>>>(W1, U1, P1, 36, 64);
        long tot2 = 32L * 2 * 64 * 512;
        pack32_kernel<<<(int)((tot2 + 255) / 256), 256, 0, stream>>>(W2, U2, P2, 64, 512);
    }

    // 256 blocks = 1 block/CU: co-residency guaranteed, plain launch.
    lstm_persist<<<256, 256, 0, stream>>>(xb, P1, P2, b1, b2, h1r, h2r, cnt1, cnt2);

    dense_kernel<<<B_, 64, 0, stream>>>(h2r + (size_t)((T_ - 1) & 3) * BU_,
                                        Wd, bd, out);
}

// Round 4
// 7210.307 us; speedup vs baseline: 1.1968x; 1.1968x over previous
//
#include <hip/hip_runtime.h>
#include <hip/hip_bf16.h>

#define B_  256
#define T_  256
#define F_  64
#define U_  512
#define NG_ 2048   // 4*U
#define BU_ (B_ * U_)

typedef __attribute__((ext_vector_type(8))) short short8;
typedef __attribute__((ext_vector_type(16))) float floatx16;

__device__ __forceinline__ unsigned short f2bf(float f) {
    union { float f; unsigned int u; } v; v.f = f;
    unsigned int u = v.u;
    return (unsigned short)((u + 0x7FFFu + ((u >> 16) & 1u)) >> 16);
}
__device__ __forceinline__ float bf2f(unsigned short s) {
    union { unsigned int u; float f; } v; v.u = ((unsigned int)s) << 16;
    return v.f;
}

__global__ void cast_x_kernel(const float* __restrict__ x,
                              unsigned short* __restrict__ xb, int n) {
    int i = blockIdx.x * blockDim.x + threadIdx.x;
    if (i < n) xb[i] = f2bf(x[i]);
}

// Pack weights into 32x32x16 MFMA B-fragments, per unit-group (16 units -> 64
// block-local gate cols = 2 n32 tiles: [i16|f16] [g16|o16]).
// dst[(((ug*2+nt)*KT + kt)*512) + lane*8 + j] =
//    M[k = kt*16 + (lane>>5)*8 + j][n = (c>>4)*512 + ug*16 + (c&15)], c=nt*32+(lane&31)
// k < KX -> W, else Uw.  (self-consistent A/B k-permutation cancels in MFMA)
__global__ void pack32_kernel(const float* __restrict__ W, const float* __restrict__ Uw,
                              unsigned short* __restrict__ dst, int KT, int KX) {
    long tid = (long)blockIdx.x * blockDim.x + threadIdx.x;
    long total = 32L * 2 * KT * 512;
    if (tid >= total) return;
    int j    = (int)(tid & 7);
    int lane = (int)((tid >> 3) & 63);
    int p512 = (int)(tid >> 9);
    int kt   = p512 % KT;
    int q    = p512 / KT;
    int nt   = q & 1;
    int ug   = q >> 1;
    int c    = nt * 32 + (lane & 31);
    int srcn = (c >> 4) * U_ + ug * 16 + (c & 15);
    int k    = kt * 16 + (lane >> 5) * 8 + j;
    float v  = (k < KX) ? W[(long)k * NG_ + srcn] : Uw[(long)(k - KX) * NG_ + srcn];
    dst[tid] = f2bf(v);
}

// Lane-parallel flag wait: lanes 0..31 poll flags[0..31]; RELAXED polls, one
// ACQUIRE fence after success. All 4 waves call this.
__device__ __forceinline__ void wait_flags(const int* flags, int target, int lane) {
    if (target <= 0) { __builtin_amdgcn_fence(__ATOMIC_ACQUIRE, "agent"); return; }
    const int* p = flags + (lane & 31);
    int guard = 0;
    for (;;) {
        int v = __hip_atomic_load(p, __ATOMIC_RELAXED, __HIP_MEMORY_SCOPE_AGENT);
        if (__ballot(v >= target) == ~0ull) break;
        __builtin_amdgcn_s_sleep(1);
        if (++guard > (1 << 22)) break;   // fail visibly, never hang
    }
    __builtin_amdgcn_fence(__ATOMIC_ACQUIRE, "agent");
}

#define MFMA32(a, b, c) __builtin_amdgcn_mfma_f32_32x32x16_bf16(a, b, c, 0, 0, 0)

// Persistent 2-layer LSTM. 256 blocks x 256 thr = 1 block/CU.
// mo = bid % 8  -> all 32 blocks of an m-octile share one XCD (bid%8 = XCD):
// h/flag traffic stays XCD-local. ug = bid / 8.
// iter k: phase A = L1 step k, phase B = L2 step k-1. Weights in VGPRs.
__global__ __launch_bounds__(256, 1) void lstm_persist(
    const unsigned short* __restrict__ xb,
    const unsigned short* __restrict__ P1,
    const unsigned short* __restrict__ P2,
    const float* __restrict__ b1, const float* __restrict__ b2,
    unsigned short* __restrict__ h1r, unsigned short* __restrict__ h2r,
    int* flags1, int* flags2)
{
    const int bid  = blockIdx.x;     // 0..255
    const int mo   = bid & 7;        // m-octile == XCD
    const int ug   = bid >> 3;       // 32 unit-groups of 16 units
    const int tid  = threadIdx.x;
    const int w    = tid >> 6;       // wave 0..3 (k-split)
    const int lane = tid & 63;
    const int arow = lane & 31;
    const int koff = (lane >> 5) * 8;
    const int row  = mo * 32 + arow;

    int* f1 = flags1 + mo * 32;      // flag1[ug] = k+1  <=>  h1[k] ready
    int* f2 = flags2 + mo * 32;      // flag2[ug] = t2+1 <=>  h2[t2] ready

    __shared__ float red[4][2][32][33];   // padded: kills 4-way bank conflicts
    __shared__ float cst1[32][16];
    __shared__ float cst2[32][16];
    __shared__ float bias1_s[64], bias2_s[64];

    for (int i = tid; i < 512; i += 256) {
        cst1[i >> 4][i & 15] = 0.f;
        cst2[i >> 4][i & 15] = 0.f;
    }
    if (tid < 64) {
        bias1_s[tid] = b1[(tid >> 4) * U_ + ug * 16 + (tid & 15)];
        bias2_s[tid] = b2[(tid >> 4) * U_ + ug * 16 + (tid & 15)];
    }

    // ---- load BOTH layers' B-fragments into registers (once) ----
    short8 a1f0[9], a1f1[9];     // L1: 36 ktiles of K=16, 9 per wave
    {
        const unsigned short* base = P1 + (size_t)ug * (2 * 36 * 512);
        #pragma unroll
        for (int i = 0; i < 9; ++i) {
            a1f0[i] = *(const short8*)(base + ((size_t)(0 * 36 + w * 9 + i) * 64 + lane) * 8);
            a1f1[i] = *(const short8*)(base + ((size_t)(1 * 36 + w * 9 + i) * 64 + lane) * 8);
        }
    }
    short8 b2f0[16], b2f1[16];   // L2: 64 ktiles; w0,w1 -> U2 half; w2,w3 -> W2 half
    {
        const unsigned short* base = P2 + (size_t)ug * (2 * 64 * 512);
        const int fb = (w < 2) ? (32 + w * 16) : ((w - 2) * 16);
        #pragma unroll
        for (int i = 0; i < 16; ++i) {
            b2f0[i] = *(const short8*)(base + ((size_t)(0 * 64 + fb + i) * 64 + lane) * 8);
            b2f1[i] = *(const short8*)(base + ((size_t)(1 * 64 + fb + i) * 64 + lane) * 8);
        }
    }
    __syncthreads();

    for (int k = 0; k <= T_; ++k) {
        // ================= phase A : layer-1 step t = k =================
        if (k < T_) {
            wait_flags(f1, k, lane);        // h1[k-1] ready from all 32 ug blocks

            floatx16 acc0, acc1;
            #pragma unroll
            for (int i = 0; i < 16; ++i) { acc0[i] = 0.f; acc1[i] = 0.f; }

            if (w == 0) {
                const unsigned short* xbase = xb + ((size_t)row * T_ + k) * F_;
                #pragma unroll
                for (int i = 0; i < 4; ++i) {
                    short8 a = *(const short8*)(xbase + i * 16 + koff);
                    acc0 = MFMA32(a, a1f0[i], acc0);
                    acc1 = MFMA32(a, a1f1[i], acc1);
                }
                if (k > 0) {
                    const unsigned short* hb = h1r + (size_t)((k - 1) & 3) * BU_
                                               + (size_t)row * U_;
                    #pragma unroll
                    for (int i = 4; i < 9; ++i) {
                        short8 a = *(const short8*)(hb + (i - 4) * 16 + koff);
                        acc0 = MFMA32(a, a1f0[i], acc0);
                        acc1 = MFMA32(a, a1f1[i], acc1);
                    }
                }
            } else if (k > 0) {
                const unsigned short* hb = h1r + (size_t)((k - 1) & 3) * BU_
                                           + (size_t)row * U_ + (w * 9 - 4) * 16;
                #pragma unroll
                for (int i = 0; i < 9; ++i) {
                    short8 a = *(const short8*)(hb + i * 16 + koff);
                    acc0 = MFMA32(a, a1f0[i], acc0);
                    acc1 = MFMA32(a, a1f1[i], acc1);
                }
            }

            // D layout: col=lane&31, row=(r&3)+8*(r>>2)+4*(lane>>5)
            #pragma unroll
            for (int r = 0; r < 16; ++r) {
                int rr = (r & 3) + 8 * (r >> 2) + 4 * (lane >> 5);
                red[w][0][rr][arow] = acc0[r];
                red[w][1][rr][arow] = acc1[r];
            }
            __syncthreads();

            {   // epilogue: 256 thr x 2 rows
                int u  = tid & 15;
                int r0 = tid >> 4;
                unsigned short* hout = h1r + (size_t)(k & 3) * BU_;
                #pragma unroll
                for (int rh = 0; rh < 2; ++rh) {
                    int r = r0 + rh * 16;
                    float zi = 0.f, zf = 0.f, zg = 0.f, zo = 0.f;
                    #pragma unroll
                    for (int ww = 0; ww < 4; ++ww) {
                        zi += red[ww][0][r][u];
                        zf += red[ww][0][r][16 + u];
                        zg += red[ww][1][r][u];
                        zo += red[ww][1][r][16 + u];
                    }
                    zi += bias1_s[u];      zf += bias1_s[16 + u];
                    zg += bias1_s[32 + u]; zo += bias1_s[48 + u];
                    float si = 1.f / (1.f + __expf(-zi));
                    float sf = 1.f / (1.f + __expf(-zf));
                    float so = 1.f / (1.f + __expf(-zo));
                    float gg = zg > 0.f ? zg : 0.f;
                    float cn = sf * cst1[r][u] + si * gg;
                    cst1[r][u] = cn;
                    float hn = so * (cn > 0.f ? cn : 0.f);
                    hout[(size_t)(mo * 32 + r) * U_ + ug * 16 + u] = f2bf(hn);
                }
            }
            __syncthreads();   // all waves' h1 stores drained (vmcnt0 in barrier)
            if (tid == 0) {
                __builtin_amdgcn_fence(__ATOMIC_RELEASE, "agent");
                __hip_atomic_store(f1 + ug, k + 1, __ATOMIC_RELAXED,
                                   __HIP_MEMORY_SCOPE_AGENT);
            }
        }

        // ================= phase B : layer-2 step t2 = k-1 =================
        if (k >= 1) {
            const int t2 = k - 1;
            wait_flags(f2, t2, lane);       // h2[t2-1] ready (1-iter slack, usually free)

            floatx16 acc0, acc1;
            #pragma unroll
            for (int i = 0; i < 16; ++i) { acc0[i] = 0.f; acc1[i] = 0.f; }

            if (w < 2) {
                if (t2 > 0) {               // U2 * h2[t2-1] half
                    const unsigned short* hb = h2r + (size_t)((t2 - 1) & 3) * BU_
                                               + (size_t)row * U_ + (w * 16) * 16;
                    #pragma unroll
                    for (int i = 0; i < 16; ++i) {
                        short8 a = *(const short8*)(hb + i * 16 + koff);
                        acc0 = MFMA32(a, b2f0[i], acc0);
                        acc1 = MFMA32(a, b2f1[i], acc1);
                    }
                }
            } else {
                // W2 * h1[t2] half — flag1[t2] observed by this iter's phase-A wait
                const unsigned short* hb = h1r + (size_t)(t2 & 3) * BU_
                                           + (size_t)row * U_ + ((w - 2) * 16) * 16;
                #pragma unroll
                for (int i = 0; i < 16; ++i) {
                    short8 a = *(const short8*)(hb + i * 16 + koff);
                    acc0 = MFMA32(a, b2f0[i], acc0);
                    acc1 = MFMA32(a, b2f1[i], acc1);
                }
            }

            #pragma unroll
            for (int r = 0; r < 16; ++r) {
                int rr = (r & 3) + 8 * (r >> 2) + 4 * (lane >> 5);
                red[w][0][rr][arow] = acc0[r];
                red[w][1][rr][arow] = acc1[r];
            }
            __syncthreads();

            {
                int u  = tid & 15;
                int r0 = tid >> 4;
                unsigned short* hout = h2r + (size_t)(t2 & 3) * BU_;
                #pragma unroll
                for (int rh = 0; rh < 2; ++rh) {
                    int r = r0 + rh * 16;
                    float zi = 0.f, zf = 0.f, zg = 0.f, zo = 0.f;
                    #pragma unroll
                    for (int ww = 0; ww < 4; ++ww) {
                        zi += red[ww][0][r][u];
                        zf += red[ww][0][r][16 + u];
                        zg += red[ww][1][r][u];
                        zo += red[ww][1][r][16 + u];
                    }
                    zi += bias2_s[u];      zf += bias2_s[16 + u];
                    zg += bias2_s[32 + u]; zo += bias2_s[48 + u];
                    float si = 1.f / (1.f + __expf(-zi));
                    float sf = 1.f / (1.f + __expf(-zf));
                    float so = 1.f / (1.f + __expf(-zo));
                    float gg = zg > 0.f ? zg : 0.f;
                    float cn = sf * cst2[r][u] + si * gg;
                    cst2[r][u] = cn;
                    float hn = so * (cn > 0.f ? cn : 0.f);
                    hout[(size_t)(mo * 32 + r) * U_ + ug * 16 + u] = f2bf(hn);
                }
            }
            __syncthreads();
            if (tid == 0) {
                __builtin_amdgcn_fence(__ATOMIC_RELEASE, "agent");
                __hip_atomic_store(f2 + ug, t2 + 1, __ATOMIC_RELAXED,
                                   __HIP_MEMORY_SCOPE_AGENT);
            }
        }
    }
}

__global__ void dense_kernel(const unsigned short* __restrict__ h2,
                             const float* __restrict__ Wd,
                             const float* __restrict__ bd,
                             float* __restrict__ out) {
    int b = blockIdx.x;
    int lane = threadIdx.x;                  // 64 lanes
    const unsigned short* hp = h2 + (long)b * U_ + lane * 8;
    float sum = 0.f;
    #pragma unroll
    for (int j = 0; j < 8; ++j) sum += bf2f(hp[j]) * Wd[lane * 8 + j];
    #pragma unroll
    for (int off = 32; off; off >>= 1) sum += __shfl_down(sum, off);
    if (lane == 0) out[b] = 1.f / (1.f + __expf(-(sum + bd[0])));
}

extern "C" void kernel_launch(void* const* d_in, const int* in_sizes, int n_in,
                              void* d_out, int out_size, void* d_ws, size_t ws_size,
                              hipStream_t stream) {
    const float* x  = (const float*)d_in[0];
    const float* W1 = (const float*)d_in[1];
    const float* U1 = (const float*)d_in[2];
    const float* b1 = (const float*)d_in[3];
    const float* W2 = (const float*)d_in[4];
    const float* U2 = (const float*)d_in[5];
    const float* b2 = (const float*)d_in[6];
    const float* Wd = (const float*)d_in[7];
    const float* bd = (const float*)d_in[8];
    float* out = (float*)d_out;

    char* ws = (char*)d_ws;
    size_t off = 0;
    unsigned short* xb  = (unsigned short*)(ws + off); off += (size_t)B_ * T_ * F_ * 2;      // 8.39 MB
    unsigned short* P1  = (unsigned short*)(ws + off); off += (size_t)32 * 2 * 36 * 512 * 2; // 2.36 MB
    unsigned short* P2  = (unsigned short*)(ws + off); off += (size_t)32 * 2 * 64 * 512 * 2; // 4.19 MB
    unsigned short* h1r = (unsigned short*)(ws + off); off += (size_t)4 * BU_ * 2;           // 1 MB
    unsigned short* h2r = (unsigned short*)(ws + off); off += (size_t)4 * BU_ * 2;           // 1 MB
    int* flags1 = (int*)(ws + off); off += (size_t)8 * 32 * 4;
    int* flags2 = (int*)(ws + off); off += (size_t)8 * 32 * 4;

    hipMemsetAsync(flags1, 0, (size_t)8 * 32 * 4 * 2, stream);

    int n = B_ * T_ * F_;
    cast_x_kernel<<<(n + 255) / 256, 256, 0, stream>>>(x, xb, n);
    {
        long tot1 = 32L * 2 * 36 * 512;
        pack32_kernel<<<(int)((tot1 + 255) / 256), 256, 0, stream>>>(W1, U1, P1, 36, 64);
        long tot2 = 32L * 2 * 64 * 512;
        pack32_kernel<<<(int)((tot2 + 255) / 256), 256, 0, stream>>>(W2, U2, P2, 64, 512);
    }

    // 256 blocks = 1 block/CU: co-residency guaranteed, plain launch.
    lstm_persist<<<256, 256, 0, stream>>>(xb, P1, P2, b1, b2, h1r, h2r, flags1, flags2);

    dense_kernel<<<B_, 64, 0, stream>>>(h2r + (size_t)((T_ - 1) & 3) * BU_,
                                        Wd, bd, out);
}

// Round 5
// 2388.339 us; speedup vs baseline: 3.6130x; 3.0190x over previous
//
#include <hip/hip_runtime.h>
#include <hip/hip_bf16.h>

#define B_  256
#define T_  256
#define F_  64
#define U_  512
#define NG_ 2048   // 4*U
#define BU_ (B_ * U_)

typedef __attribute__((ext_vector_type(8))) short short8;
typedef __attribute__((ext_vector_type(16))) float floatx16;

__device__ __forceinline__ unsigned short f2bf(float f) {
    union { float f; unsigned int u; } v; v.f = f;
    unsigned int u = v.u;
    return (unsigned short)((u + 0x7FFFu + ((u >> 16) & 1u)) >> 16);
}
__device__ __forceinline__ float bf2f(unsigned short s) {
    union { unsigned int u; float f; } v; v.u = ((unsigned int)s) << 16;
    return v.f;
}

__global__ void cast_x_kernel(const float* __restrict__ x,
                              unsigned short* __restrict__ xb, int n) {
    int i = blockIdx.x * blockDim.x + threadIdx.x;
    if (i < n) xb[i] = f2bf(x[i]);
}

// Pack weights into 32x32x16 MFMA B-fragments, per unit-group (16 units -> 64
// block-local gate cols = 2 n32 tiles: [i16|f16] [g16|o16]).
// dst[(((ug*2+nt)*KT + kt)*512) + lane*8 + j] =
//    M[k = kt*16 + (lane>>5)*8 + j][n = (c>>4)*512 + ug*16 + (c&15)], c=nt*32+(lane&31)
__global__ void pack32_kernel(const float* __restrict__ W, const float* __restrict__ Uw,
                              unsigned short* __restrict__ dst, int KT, int KX) {
    long tid = (long)blockIdx.x * blockDim.x + threadIdx.x;
    long total = 32L * 2 * KT * 512;
    if (tid >= total) return;
    int j    = (int)(tid & 7);
    int lane = (int)((tid >> 3) & 63);
    int p512 = (int)(tid >> 9);
    int kt   = p512 % KT;
    int q    = p512 / KT;
    int nt   = q & 1;
    int ug   = q >> 1;
    int c    = nt * 32 + (lane & 31);
    int srcn = (c >> 4) * U_ + ug * 16 + (c & 15);
    int k    = kt * 16 + (lane >> 5) * 8 + j;
    float v  = (k < KX) ? W[(long)k * NG_ + srcn] : Uw[(long)(k - KX) * NG_ + srcn];
    dst[tid] = f2bf(v);
}

// Lane-parallel flag wait. RELAXED sc1 polls straight to LLC; NO hardware
// fence (acquire = control dep + compiler fence; data loads are sc1 too).
__device__ __forceinline__ void wait_flags(const int* flags, int target, int lane) {
    if (target > 0) {
        const int* p = flags + (lane & 31);
        int guard = 0;
        for (;;) {
            int v = __hip_atomic_load(p, __ATOMIC_RELAXED, __HIP_MEMORY_SCOPE_AGENT);
            if (__ballot(v >= target) == ~0ull) break;
            __builtin_amdgcn_s_sleep(1);
            if (++guard > (1 << 21)) break;   // fail visibly, never hang
        }
    }
    __atomic_signal_fence(__ATOMIC_ACQUIRE);  // compiler-only, no instructions
}

// 16-B h-fragment load as 2x u64 relaxed agent atomics -> global_load_dwordx2
// sc1 (LLC-coherent, bypasses possibly-stale L1/L2, no cache maintenance).
__device__ __forceinline__ short8 ld_frag(const unsigned short* p) {
    union { unsigned long long q[2]; short8 v; } u;
    const unsigned long long* qp = (const unsigned long long*)p;
    u.q[0] = __hip_atomic_load(qp,     __ATOMIC_RELAXED, __HIP_MEMORY_SCOPE_AGENT);
    u.q[1] = __hip_atomic_load(qp + 1, __ATOMIC_RELAXED, __HIP_MEMORY_SCOPE_AGENT);
    return u.v;
}

#define MFMA32(a, b, c) __builtin_amdgcn_mfma_f32_32x32x16_bf16(a, b, c, 0, 0, 0)

// Persistent 2-layer LSTM. 256 blocks x 256 thr = 1 block/CU.
// mo = bid % 8 -> communicating blocks share an XCD (perf heuristic only;
// correctness is LLC-level). iter k: phase A = L1 step k, phase B = L2 step
// k-1. Weights in VGPRs. NO cache-maintenance ops anywhere in the loop.
__global__ __launch_bounds__(256, 1) void lstm_persist(
    const unsigned short* __restrict__ xb,
    const unsigned short* __restrict__ P1,
    const unsigned short* __restrict__ P2,
    const float* __restrict__ b1, const float* __restrict__ b2,
    unsigned short* __restrict__ h1r, unsigned short* __restrict__ h2r,
    int* flags1, int* flags2)
{
    const int bid  = blockIdx.x;     // 0..255
    const int mo   = bid & 7;        // m-octile == XCD
    const int ug   = bid >> 3;       // 32 unit-groups of 16 units
    const int tid  = threadIdx.x;
    const int w    = tid >> 6;       // wave 0..3 (k-split)
    const int lane = tid & 63;
    const int arow = lane & 31;
    const int koff = (lane >> 5) * 8;
    const int row  = mo * 32 + arow;

    int* f1 = flags1 + mo * 32;      // flag1[ug] = k+1  <=>  h1[k] ready
    int* f2 = flags2 + mo * 32;      // flag2[ug] = t2+1 <=>  h2[t2] ready

    __shared__ float red[4][2][32][33];   // padded vs bank conflicts
    __shared__ float cst1[32][16];
    __shared__ float cst2[32][16];
    __shared__ float bias1_s[64], bias2_s[64];

    for (int i = tid; i < 512; i += 256) {
        cst1[i >> 4][i & 15] = 0.f;
        cst2[i >> 4][i & 15] = 0.f;
    }
    if (tid < 64) {
        bias1_s[tid] = b1[(tid >> 4) * U_ + ug * 16 + (tid & 15)];
        bias2_s[tid] = b2[(tid >> 4) * U_ + ug * 16 + (tid & 15)];
    }

    // ---- load BOTH layers' B-fragments into registers (once) ----
    short8 a1f0[9], a1f1[9];     // L1: 36 ktiles of K=16, 9 per wave
    {
        const unsigned short* base = P1 + (size_t)ug * (2 * 36 * 512);
        #pragma unroll
        for (int i = 0; i < 9; ++i) {
            a1f0[i] = *(const short8*)(base + ((size_t)(0 * 36 + w * 9 + i) * 64 + lane) * 8);
            a1f1[i] = *(const short8*)(base + ((size_t)(1 * 36 + w * 9 + i) * 64 + lane) * 8);
        }
    }
    short8 b2f0[16], b2f1[16];   // L2: 64 ktiles; w0,w1 -> U2 half; w2,w3 -> W2 half
    {
        const unsigned short* base = P2 + (size_t)ug * (2 * 64 * 512);
        const int fb = (w < 2) ? (32 + w * 16) : ((w - 2) * 16);
        #pragma unroll
        for (int i = 0; i < 16; ++i) {
            b2f0[i] = *(const short8*)(base + ((size_t)(0 * 64 + fb + i) * 64 + lane) * 8);
            b2f1[i] = *(const short8*)(base + ((size_t)(1 * 64 + fb + i) * 64 + lane) * 8);
        }
    }
    __syncthreads();

    for (int k = 0; k <= T_; ++k) {
        // ================= phase A : layer-1 step t = k =================
        if (k < T_) {
            wait_flags(f1, k, lane);        // h1[k-1] ready from all 32 ug blocks

            floatx16 acc0, acc1;
            #pragma unroll
            for (int i = 0; i < 16; ++i) { acc0[i] = 0.f; acc1[i] = 0.f; }

            if (w == 0) {
                const unsigned short* xbase = xb + ((size_t)row * T_ + k) * F_;
                #pragma unroll
                for (int i = 0; i < 4; ++i) {
                    short8 a = *(const short8*)(xbase + i * 16 + koff);  // x: plain cached
                    acc0 = MFMA32(a, a1f0[i], acc0);
                    acc1 = MFMA32(a, a1f1[i], acc1);
                }
                if (k > 0) {
                    const unsigned short* hb = h1r + (size_t)((k - 1) & 3) * BU_
                                               + (size_t)row * U_;
                    #pragma unroll
                    for (int i = 4; i < 9; ++i) {
                        short8 a = ld_frag(hb + (i - 4) * 16 + koff);
                        acc0 = MFMA32(a, a1f0[i], acc0);
                        acc1 = MFMA32(a, a1f1[i], acc1);
                    }
                }
            } else if (k > 0) {
                const unsigned short* hb = h1r + (size_t)((k - 1) & 3) * BU_
                                           + (size_t)row * U_ + (w * 9 - 4) * 16;
                #pragma unroll
                for (int i = 0; i < 9; ++i) {
                    short8 a = ld_frag(hb + i * 16 + koff);
                    acc0 = MFMA32(a, a1f0[i], acc0);
                    acc1 = MFMA32(a, a1f1[i], acc1);
                }
            }

            // D layout: col=lane&31, row=(r&3)+8*(r>>2)+4*(lane>>5)
            #pragma unroll
            for (int r = 0; r < 16; ++r) {
                int rr = (r & 3) + 8 * (r >> 2) + 4 * (lane >> 5);
                red[w][0][rr][arow] = acc0[r];
                red[w][1][rr][arow] = acc1[r];
            }
            __syncthreads();

            {   // epilogue: 256 thr = 32 rows x 8 unit-pairs; one u32 store
                int u2 = (tid & 7) * 2;
                int r  = tid >> 3;
                unsigned int pk = 0;
                #pragma unroll
                for (int du = 0; du < 2; ++du) {
                    int u = u2 + du;
                    float zi = 0.f, zf = 0.f, zg = 0.f, zo = 0.f;
                    #pragma unroll
                    for (int ww = 0; ww < 4; ++ww) {
                        zi += red[ww][0][r][u];
                        zf += red[ww][0][r][16 + u];
                        zg += red[ww][1][r][u];
                        zo += red[ww][1][r][16 + u];
                    }
                    zi += bias1_s[u];      zf += bias1_s[16 + u];
                    zg += bias1_s[32 + u]; zo += bias1_s[48 + u];
                    float si = 1.f / (1.f + __expf(-zi));
                    float sf = 1.f / (1.f + __expf(-zf));
                    float so = 1.f / (1.f + __expf(-zo));
                    float gg = zg > 0.f ? zg : 0.f;
                    float cn = sf * cst1[r][u] + si * gg;
                    cst1[r][u] = cn;
                    float hn = so * (cn > 0.f ? cn : 0.f);
                    pk |= ((unsigned int)f2bf(hn)) << (16 * du);
                }
                unsigned int* hp = (unsigned int*)(h1r + (size_t)(k & 3) * BU_
                                   + (size_t)(mo * 32 + r) * U_ + ug * 16 + u2);
                __hip_atomic_store(hp, pk, __ATOMIC_RELAXED, __HIP_MEMORY_SCOPE_AGENT);
            }
            __syncthreads();   // every wave's sc1 h-stores drained (vmcnt0) at barrier
            __atomic_signal_fence(__ATOMIC_RELEASE);
            if (tid == 0)
                __hip_atomic_store(f1 + ug, k + 1, __ATOMIC_RELAXED,
                                   __HIP_MEMORY_SCOPE_AGENT);
        }

        // ================= phase B : layer-2 step t2 = k-1 =================
        if (k >= 1) {
            const int t2 = k - 1;
            wait_flags(f2, t2, lane);       // h2[t2-1] ready

            floatx16 acc0, acc1;
            #pragma unroll
            for (int i = 0; i < 16; ++i) { acc0[i] = 0.f; acc1[i] = 0.f; }

            if (w < 2) {
                if (t2 > 0) {               // U2 * h2[t2-1] half
                    const unsigned short* hb = h2r + (size_t)((t2 - 1) & 3) * BU_
                                               + (size_t)row * U_ + (w * 16) * 16;
                    #pragma unroll
                    for (int i = 0; i < 16; ++i) {
                        short8 a = ld_frag(hb + i * 16 + koff);
                        acc0 = MFMA32(a, b2f0[i], acc0);
                        acc1 = MFMA32(a, b2f1[i], acc1);
                    }
                }
            } else {
                // W2 * h1[t2] half — ready: phase A this iter waited flag1 >= t2+1
                const unsigned short* hb = h1r + (size_t)(t2 & 3) * BU_
                                           + (size_t)row * U_ + ((w - 2) * 16) * 16;
                #pragma unroll
                for (int i = 0; i < 16; ++i) {
                    short8 a = ld_frag(hb + i * 16 + koff);
                    acc0 = MFMA32(a, b2f0[i], acc0);
                    acc1 = MFMA32(a, b2f1[i], acc1);
                }
            }

            #pragma unroll
            for (int r = 0; r < 16; ++r) {
                int rr = (r & 3) + 8 * (r >> 2) + 4 * (lane >> 5);
                red[w][0][rr][arow] = acc0[r];
                red[w][1][rr][arow] = acc1[r];
            }
            __syncthreads();

            {
                int u2 = (tid & 7) * 2;
                int r  = tid >> 3;
                unsigned int pk = 0;
                #pragma unroll
                for (int du = 0; du < 2; ++du) {
                    int u = u2 + du;
                    float zi = 0.f, zf = 0.f, zg = 0.f, zo = 0.f;
                    #pragma unroll
                    for (int ww = 0; ww < 4; ++ww) {
                        zi += red[ww][0][r][u];
                        zf += red[ww][0][r][16 + u];
                        zg += red[ww][1][r][u];
                        zo += red[ww][1][r][16 + u];
                    }
                    zi += bias2_s[u];      zf += bias2_s[16 + u];
                    zg += bias2_s[32 + u]; zo += bias2_s[48 + u];
                    float si = 1.f / (1.f + __expf(-zi));
                    float sf = 1.f / (1.f + __expf(-zf));
                    float so = 1.f / (1.f + __expf(-zo));
                    float gg = zg > 0.f ? zg : 0.f;
                    float cn = sf * cst2[r][u] + si * gg;
                    cst2[r][u] = cn;
                    float hn = so * (cn > 0.f ? cn : 0.f);
                    pk |= ((unsigned int)f2bf(hn)) << (16 * du);
                }
                unsigned int* hp = (unsigned int*)(h2r + (size_t)(t2 & 3) * BU_
                                   + (size_t)(mo * 32 + r) * U_ + ug * 16 + u2);
                __hip_atomic_store(hp, pk, __ATOMIC_RELAXED, __HIP_MEMORY_SCOPE_AGENT);
            }
            __syncthreads();
            __atomic_signal_fence(__ATOMIC_RELEASE);
            if (tid == 0)
                __hip_atomic_store(f2 + ug, t2 + 1, __ATOMIC_RELAXED,
                                   __HIP_MEMORY_SCOPE_AGENT);
        }
    }
}

__global__ void dense_kernel(const unsigned short* __restrict__ h2,
                             const float* __restrict__ Wd,
                             const float* __restrict__ bd,
                             float* __restrict__ out) {
    int b = blockIdx.x;
    int lane = threadIdx.x;                  // 64 lanes
    const unsigned short* hp = h2 + (long)b * U_ + lane * 8;
    float sum = 0.f;
    #pragma unroll
    for (int j = 0; j < 8; ++j) sum += bf2f(hp[j]) * Wd[lane * 8 + j];
    #pragma unroll
    for (int off = 32; off; off >>= 1) sum += __shfl_down(sum, off);
    if (lane == 0) out[b] = 1.f / (1.f + __expf(-(sum + bd[0])));
}

extern "C" void kernel_launch(void* const* d_in, const int* in_sizes, int n_in,
                              void* d_out, int out_size, void* d_ws, size_t ws_size,
                              hipStream_t stream) {
    const float* x  = (const float*)d_in[0];
    const float* W1 = (const float*)d_in[1];
    const float* U1 = (const float*)d_in[2];
    const float* b1 = (const float*)d_in[3];
    const float* W2 = (const float*)d_in[4];
    const float* U2 = (const float*)d_in[5];
    const float* b2 = (const float*)d_in[6];
    const float* Wd = (const float*)d_in[7];
    const float* bd = (const float*)d_in[8];
    float* out = (float*)d_out;

    char* ws = (char*)d_ws;
    size_t off = 0;
    unsigned short* xb  = (unsigned short*)(ws + off); off += (size_t)B_ * T_ * F_ * 2;      // 8.39 MB
    unsigned short* P1  = (unsigned short*)(ws + off); off += (size_t)32 * 2 * 36 * 512 * 2; // 2.36 MB
    unsigned short* P2  = (unsigned short*)(ws + off); off += (size_t)32 * 2 * 64 * 512 * 2; // 4.19 MB
    unsigned short* h1r = (unsigned short*)(ws + off); off += (size_t)4 * BU_ * 2;           // 1 MB
    unsigned short* h2r = (unsigned short*)(ws + off); off += (size_t)4 * BU_ * 2;           // 1 MB
    int* flags1 = (int*)(ws + off); off += (size_t)8 * 32 * 4;
    int* flags2 = (int*)(ws + off); off += (size_t)8 * 32 * 4;

    hipMemsetAsync(flags1, 0, (size_t)8 * 32 * 4 * 2, stream);

    int n = B_ * T_ * F_;
    cast_x_kernel<<<(n + 255) / 256, 256, 0, stream>>>(x, xb, n);
    {
        long tot1 = 32L * 2 * 36 * 512;
        pack32_kernel<<<(int)((tot1 + 255) / 256), 256, 0, stream>>>(W1, U1, P1, 36, 64);
        long tot2 = 32L * 2 * 64 * 512;
        pack32_kernel<<<(int)((tot2 + 255) / 256), 256, 0, stream>>>(W2, U2, P2, 64, 512);
    }

    // 256 blocks = 1 block/CU: co-residency guaranteed, plain launch.
    lstm_persist<<<256, 256, 0, stream>>>(xb, P1, P2, b1, b2, h1r, h2r, flags1, flags2);

    dense_kernel<<<B_, 64, 0, stream>>>(h2r + (size_t)((T_ - 1) & 3) * BU_,
                                        Wd, bd, out);
}